// Round 7
// baseline (145.436 us; speedup 1.0000x reference)
//
#include <hip/hip_runtime.h>

#define BN_EPS 1e-3f

typedef float vf4 __attribute__((ext_vector_type(4)));      // native vector for builtins
typedef _Float16 half8 __attribute__((ext_vector_type(8))); // 16B of fp16

// ---- order-preserving float<->uint key for atomicMax on floats ----
__device__ __forceinline__ unsigned int f2k(float f) {
    unsigned int u = __float_as_uint(f);
    return (u & 0x80000000u) ? ~u : (u | 0x80000000u);
}
__device__ __forceinline__ float k2f(unsigned int u) {
    return __uint_as_float((u & 0x80000000u) ? (u & 0x7FFFFFFFu) : ~u);
}

// Kernel 1: per-node precompute.
//   y2h[n,s,h] = (fp16) sum_f x[n,f] * Wk[s, f*H + h]   for s<8
//   y2h[n,8,h] = (fp16) sum_f x[n,f] * bk[f*H + h]      (bias row, edge coeff 1.0)
//   agg[n,h]   = sum_f x[n,f] * Wr[f,h] + br[h]         (base folded into agg init)
// Also initializes pooled_u + done-counter (block 0).
template <int S, int F, int H>
__global__ void node_pre(const float* __restrict__ x,
                         const float* __restrict__ Wk,
                         const float* __restrict__ bk,
                         const float* __restrict__ Wr,
                         const float* __restrict__ br,
                         _Float16* __restrict__ y2h,   // [N, S+1, H] fp16
                         float* __restrict__ agg,      // [N, H] fp32
                         unsigned int* __restrict__ pooled_u,  // [H] + [1] counter
                         int N) {
    if (blockIdx.x == 0 && threadIdx.x < H + 1) pooled_u[threadIdx.x] = 0u;

    int t = blockIdx.x * blockDim.x + threadIdx.x;
    int n = t / H;
    int h = t % H;
    if (n >= N) return;

    float xf[F];
#pragma unroll
    for (int f = 0; f < F; ++f) xf[f] = x[n * F + f];

    _Float16* yrow = y2h + (size_t)n * (S + 1) * H + h;
#pragma unroll
    for (int s = 0; s < S; ++s) {
        float acc = 0.f;
#pragma unroll
        for (int f = 0; f < F; ++f) acc += xf[f] * Wk[(s * F + f) * H + h];
        yrow[s * H] = (_Float16)acc;
    }

    float accb = 0.f, accr = 0.f;
#pragma unroll
    for (int f = 0; f < F; ++f) {
        accb += xf[f] * bk[f * H + h];
        accr += xf[f] * Wr[f * H + h];
    }
    yrow[S * H] = (_Float16)accb;             // bias row (coeff 1.0 per edge)
    agg[(size_t)n * H + h] = accr + br[h];    // base folded into agg init
}

// Kernel 2: per-edge message + scatter-add. 256 edges/block, 2 edges/thread.
// Phase A: 2 lanes/edge, half8 gathers of y2h -> msg in LDS (padded stride).
// Phase B: lanes remapped edge-major (4 edges x 16 ch per wave instruction)
// so all 16 channels of an edge coalesce into 2 x 32B sectors (64 B/edge).
template <int S, int H>
__global__ void __launch_bounds__(256)
edge_scatter(const float* __restrict__ efeat,
             const int* __restrict__ src,
             const int* __restrict__ dst,
             const _Float16* __restrict__ y2h,  // [N, S+1, H]
             float* __restrict__ agg,
             int E) {
    constexpr int EB = 256;        // edges per block
    constexpr int LDW = EB + 4;    // 260: 260%32==4 -> 2-way max in both phases (free)
    __shared__ float msg[H][LDW];
    __shared__ int sdst[EB];

    int t = threadIdx.x;
    int e0 = blockIdx.x * EB;

    // ---- Phase A: gather + per-edge dense mini-GEMV, 2 edges/thread ----
    int el = t >> 1;               // 0..127
    int hi = t & 1;                // which 8-wide half of the H=16 row
    int ell0 = el, ell1 = el + 128;
    int ec0 = min(e0 + ell0, E - 1);   // clamp: loads always in-bounds,
    int ec1 = min(e0 + ell1, E - 1);   // atomics guarded in Phase B

    int sn0 = __builtin_nontemporal_load(src + ec0);
    int sn1 = __builtin_nontemporal_load(src + ec1);
    if (hi == 0) {
        sdst[ell0] = __builtin_nontemporal_load(dst + ec0);
        sdst[ell1] = __builtin_nontemporal_load(dst + ec1);
    }

    const vf4* e40 = (const vf4*)(efeat + (size_t)ec0 * S);
    const vf4* e41 = (const vf4*)(efeat + (size_t)ec1 * S);
    vf4 ea0 = __builtin_nontemporal_load(e40);
    vf4 eb0 = __builtin_nontemporal_load(e40 + 1);
    vf4 ea1 = __builtin_nontemporal_load(e41);
    vf4 eb1 = __builtin_nontemporal_load(e41 + 1);
    float es0[S + 1] = {ea0.x, ea0.y, ea0.z, ea0.w, eb0.x, eb0.y, eb0.z, eb0.w, 1.0f};
    float es1[S + 1] = {ea1.x, ea1.y, ea1.z, ea1.w, eb1.x, eb1.y, eb1.z, eb1.w, 1.0f};

    const _Float16* yb0 = y2h + (size_t)sn0 * (S + 1) * H + hi * 8;
    const _Float16* yb1 = y2h + (size_t)sn1 * (S + 1) * H + hi * 8;

    float m0[8] = {0.f, 0.f, 0.f, 0.f, 0.f, 0.f, 0.f, 0.f};
    float m1[8] = {0.f, 0.f, 0.f, 0.f, 0.f, 0.f, 0.f, 0.f};
#pragma unroll
    for (int s = 0; s <= S; ++s) {
        half8 hv0 = *(const half8*)(yb0 + s * H);
        half8 hv1 = *(const half8*)(yb1 + s * H);
#pragma unroll
        for (int j = 0; j < 8; ++j) {
            m0[j] += es0[s] * (float)hv0[j];
            m1[j] += es1[s] * (float)hv1[j];
        }
    }
#pragma unroll
    for (int j = 0; j < 8; ++j) {
        msg[hi * 8 + j][ell0] = m0[j];
        msg[hi * 8 + j][ell1] = m1[j];
    }

    __syncthreads();

    // ---- Phase B: edge-major coalesced atomics (64 B/edge in sectors) ----
    int e2 = t >> 4;               // 0..15
    int h = t & 15;
#pragma unroll
    for (int p = 0; p < 16; ++p) {
        int el2 = p * 16 + e2;
        if (e0 + el2 < E) {
            unsafeAtomicAdd(&agg[(size_t)sdst[el2] * H + h], msg[h][el2]);
        }
    }
}

// Kernel 3 (fused): h = BN(relu(agg)); global max per h; LAST block computes
// out = pooled @ Wd + bd. float4 loads over agg.
template <int H>
__global__ void __launch_bounds__(256)
bn_relu_max_final(const float* __restrict__ agg,
                  const float* __restrict__ gamma,
                  const float* __restrict__ beta,
                  const float* __restrict__ mmean,
                  const float* __restrict__ mvar,
                  unsigned int* __restrict__ pooled_u,  // [H] + [1] done-counter
                  const float* __restrict__ Wd,
                  const float* __restrict__ bd,
                  float* __restrict__ out,
                  int N, int HOUT) {
    __shared__ unsigned int smax[H];
    if (threadIdx.x < H) smax[threadIdx.x] = 0u;
    __syncthreads();

    int t = blockIdx.x * blockDim.x + threadIdx.x;
    int stride = gridDim.x * blockDim.x;   // threads, each handles a float4
    int h4 = (t & 3) * 4;                  // first channel of this lane's float4

    float sc[4], sh[4];
#pragma unroll
    for (int j = 0; j < 4; ++j) {
        float s = gamma[h4 + j] * rsqrtf(mvar[h4 + j] + BN_EPS);
        sc[j] = s;
        sh[j] = beta[h4 + j] - mmean[h4 + j] * s;
    }

    float best[4] = {-INFINITY, -INFINITY, -INFINITY, -INFINITY};
    int total4 = N * H / 4;
    const vf4* agg4 = (const vf4*)agg;
    for (int i = t; i < total4; i += stride) {
        vf4 v = agg4[i];
#pragma unroll
        for (int j = 0; j < 4; ++j) {
            float w = v[j] > 0.f ? v[j] : 0.f;   // relu
            w = w * sc[j] + sh[j];               // BN (inference)
            best[j] = fmaxf(best[j], w);
        }
    }
#pragma unroll
    for (int j = 0; j < 4; ++j) atomicMax(&smax[h4 + j], f2k(best[j]));
    __syncthreads();
    if (threadIdx.x < H) atomicMax(&pooled_u[threadIdx.x], smax[threadIdx.x]);

    // ---- last-block-does-final ----
    __threadfence();                        // make pooled_u visible device-wide
    __shared__ bool is_last;
    if (threadIdx.x == 0) {
        unsigned int done = atomicAdd(&pooled_u[H], 1u);
        is_last = (done == gridDim.x - 1);
    }
    __syncthreads();
    if (is_last && threadIdx.x < HOUT) {
        __threadfence();
        int j = threadIdx.x;
        float acc = bd[j];
#pragma unroll
        for (int hh = 0; hh < H; ++hh) {
            unsigned int u = atomicOr(&pooled_u[hh], 0u);  // device-coherent read
            acc += k2f(u) * Wd[hh * HOUT + j];
        }
        out[j] = acc;
    }
}

extern "C" void kernel_launch(void* const* d_in, const int* in_sizes, int n_in,
                              void* d_out, int out_size, void* d_ws, size_t ws_size,
                              hipStream_t stream) {
    const float* x     = (const float*)d_in[0];
    const float* e     = (const float*)d_in[1];
    const int*   src   = (const int*)d_in[2];
    const int*   dst   = (const int*)d_in[3];
    const float* Wk    = (const float*)d_in[4];
    const float* bk    = (const float*)d_in[5];
    const float* Wr    = (const float*)d_in[6];
    const float* br    = (const float*)d_in[7];
    const float* gamma = (const float*)d_in[8];
    const float* beta  = (const float*)d_in[9];
    const float* mmean = (const float*)d_in[10];
    const float* mvar  = (const float*)d_in[11];
    const float* Wd    = (const float*)d_in[12];
    const float* bd    = (const float*)d_in[13];

    constexpr int S = 8, F = 16, H = 16;
    const int E = in_sizes[2];
    const int N = in_sizes[0] / F;
    const int HOUT = in_sizes[13];  // 3

    // workspace layout
    _Float16* y2h = (_Float16*)d_ws;                       // N*(S+1)*H fp16
    float* agg = (float*)(y2h + (size_t)N * (S + 1) * H);  // N*H fp32
    unsigned int* pooled_u = (unsigned int*)(agg + (size_t)N * H);  // H + 1 (counter)

    const int T = 256;
    int nh = N * H;
    node_pre<S, F, H><<<(nh + T - 1) / T, T, 0, stream>>>(
        x, Wk, bk, Wr, br, y2h, agg, pooled_u, N);

    int eblocks = (E + 255) / 256;
    edge_scatter<S, H><<<eblocks, T, 0, stream>>>(
        e, src, dst, y2h, agg, E);

    bn_relu_max_final<H><<<240, T, 0, stream>>>(
        agg, gamma, beta, mmean, mvar, pooled_u, Wd, bd, (float*)d_out, N, HOUT);
}

// Round 8
// 139.265 us; speedup vs baseline: 1.0443x; 1.0443x over previous
//
#include <hip/hip_runtime.h>

#define BN_EPS 1e-3f

typedef float vf4 __attribute__((ext_vector_type(4)));      // native vector for builtins
typedef _Float16 half8 __attribute__((ext_vector_type(8))); // 16B of fp16

// ---- order-preserving float<->uint key for atomicMax on floats ----
__device__ __forceinline__ unsigned int f2k(float f) {
    unsigned int u = __float_as_uint(f);
    return (u & 0x80000000u) ? ~u : (u | 0x80000000u);
}
__device__ __forceinline__ float k2f(unsigned int u) {
    return __uint_as_float((u & 0x80000000u) ? (u & 0x7FFFFFFFu) : ~u);
}

// Kernel 1: per-node precompute.
//   y2h[n,s,h] = (fp16) sum_f x[n,f] * Wk[s, f*H + h]   for s<8
//   y2h[n,8,h] = (fp16) sum_f x[n,f] * bk[f*H + h]      (bias row, edge coeff 1.0)
//   agg[n,h]   = sum_f x[n,f] * Wr[f,h] + br[h]         (base folded into agg init)
// Also initializes pooled_u (block 0).
template <int S, int F, int H>
__global__ void node_pre(const float* __restrict__ x,
                         const float* __restrict__ Wk,
                         const float* __restrict__ bk,
                         const float* __restrict__ Wr,
                         const float* __restrict__ br,
                         _Float16* __restrict__ y2h,   // [N, S+1, H] fp16
                         float* __restrict__ agg,      // [N, H] fp32
                         unsigned int* __restrict__ pooled_u,  // [H]
                         int N) {
    if (blockIdx.x == 0 && threadIdx.x < H) pooled_u[threadIdx.x] = 0u;

    int t = blockIdx.x * blockDim.x + threadIdx.x;
    int n = t / H;
    int h = t % H;
    if (n >= N) return;

    float xf[F];
#pragma unroll
    for (int f = 0; f < F; ++f) xf[f] = x[n * F + f];

    _Float16* yrow = y2h + (size_t)n * (S + 1) * H + h;
#pragma unroll
    for (int s = 0; s < S; ++s) {
        float acc = 0.f;
#pragma unroll
        for (int f = 0; f < F; ++f) acc += xf[f] * Wk[(s * F + f) * H + h];
        yrow[s * H] = (_Float16)acc;
    }

    float accb = 0.f, accr = 0.f;
#pragma unroll
    for (int f = 0; f < F; ++f) {
        accb += xf[f] * bk[f * H + h];
        accr += xf[f] * Wr[f * H + h];
    }
    yrow[S * H] = (_Float16)accb;             // bias row (coeff 1.0 per edge)
    agg[(size_t)n * H + h] = accr + br[h];    // base folded into agg init
}

// Kernel 2: per-edge message + scatter-add. 256 edges/block, 2 edges/thread.
// Phase A: 2 lanes/edge, half8 gathers of y2h -> msg in LDS (padded stride).
// Phase B: lanes remapped edge-major (4 edges x 16 ch per wave instruction)
// so all 16 channels of an edge coalesce into 2 x 32B sectors (64 B/edge).
template <int S, int H>
__global__ void __launch_bounds__(256)
edge_scatter(const float* __restrict__ efeat,
             const int* __restrict__ src,
             const int* __restrict__ dst,
             const _Float16* __restrict__ y2h,  // [N, S+1, H]
             float* __restrict__ agg,
             int E) {
    constexpr int EB = 256;        // edges per block
    constexpr int LDW = EB + 4;    // 260: 260%32==4 -> 2-way max in both phases (free)
    __shared__ float msg[H][LDW];
    __shared__ int sdst[EB];

    int t = threadIdx.x;
    int e0 = blockIdx.x * EB;

    // ---- Phase A: gather + per-edge dense mini-GEMV, 2 edges/thread ----
    int el = t >> 1;               // 0..127
    int hi = t & 1;                // which 8-wide half of the H=16 row
    int ell0 = el, ell1 = el + 128;
    int ec0 = min(e0 + ell0, E - 1);   // clamp: loads always in-bounds,
    int ec1 = min(e0 + ell1, E - 1);   // atomics guarded in Phase B

    int sn0 = __builtin_nontemporal_load(src + ec0);
    int sn1 = __builtin_nontemporal_load(src + ec1);
    if (hi == 0) {
        sdst[ell0] = __builtin_nontemporal_load(dst + ec0);
        sdst[ell1] = __builtin_nontemporal_load(dst + ec1);
    }

    const vf4* e40 = (const vf4*)(efeat + (size_t)ec0 * S);
    const vf4* e41 = (const vf4*)(efeat + (size_t)ec1 * S);
    vf4 ea0 = __builtin_nontemporal_load(e40);
    vf4 eb0 = __builtin_nontemporal_load(e40 + 1);
    vf4 ea1 = __builtin_nontemporal_load(e41);
    vf4 eb1 = __builtin_nontemporal_load(e41 + 1);
    float es0[S + 1] = {ea0.x, ea0.y, ea0.z, ea0.w, eb0.x, eb0.y, eb0.z, eb0.w, 1.0f};
    float es1[S + 1] = {ea1.x, ea1.y, ea1.z, ea1.w, eb1.x, eb1.y, eb1.z, eb1.w, 1.0f};

    const _Float16* yb0 = y2h + (size_t)sn0 * (S + 1) * H + hi * 8;
    const _Float16* yb1 = y2h + (size_t)sn1 * (S + 1) * H + hi * 8;

    float m0[8] = {0.f, 0.f, 0.f, 0.f, 0.f, 0.f, 0.f, 0.f};
    float m1[8] = {0.f, 0.f, 0.f, 0.f, 0.f, 0.f, 0.f, 0.f};
#pragma unroll
    for (int s = 0; s <= S; ++s) {
        half8 hv0 = *(const half8*)(yb0 + s * H);
        half8 hv1 = *(const half8*)(yb1 + s * H);
#pragma unroll
        for (int j = 0; j < 8; ++j) {
            m0[j] += es0[s] * (float)hv0[j];
            m1[j] += es1[s] * (float)hv1[j];
        }
    }
#pragma unroll
    for (int j = 0; j < 8; ++j) {
        msg[hi * 8 + j][ell0] = m0[j];
        msg[hi * 8 + j][ell1] = m1[j];
    }

    __syncthreads();

    // ---- Phase B: edge-major coalesced atomics (64 B/edge in sectors) ----
    int e2 = t >> 4;               // 0..15
    int h = t & 15;
#pragma unroll
    for (int p = 0; p < 16; ++p) {
        int el2 = p * 16 + e2;
        if (e0 + el2 < E) {
            unsafeAtomicAdd(&agg[(size_t)sdst[el2] * H + h], msg[h][el2]);
        }
    }
}

// Kernel 3: h = BN(relu(agg)); global max per h. float4 loads over agg.
template <int H>
__global__ void __launch_bounds__(256)
bn_relu_max(const float* __restrict__ agg,
            const float* __restrict__ gamma,
            const float* __restrict__ beta,
            const float* __restrict__ mmean,
            const float* __restrict__ mvar,
            unsigned int* __restrict__ pooled_u,
            int N) {
    __shared__ unsigned int smax[H];
    if (threadIdx.x < H) smax[threadIdx.x] = 0u;
    __syncthreads();

    int t = blockIdx.x * blockDim.x + threadIdx.x;
    int stride = gridDim.x * blockDim.x;   // threads, each handles a float4
    int h4 = (t & 3) * 4;                  // first channel of this lane's float4

    float sc[4], sh[4];
#pragma unroll
    for (int j = 0; j < 4; ++j) {
        float s = gamma[h4 + j] * rsqrtf(mvar[h4 + j] + BN_EPS);
        sc[j] = s;
        sh[j] = beta[h4 + j] - mmean[h4 + j] * s;
    }

    float best[4] = {-INFINITY, -INFINITY, -INFINITY, -INFINITY};
    int total4 = N * H / 4;
    const vf4* agg4 = (const vf4*)agg;
    for (int i = t; i < total4; i += stride) {
        vf4 v = agg4[i];
#pragma unroll
        for (int j = 0; j < 4; ++j) {
            float w = v[j] > 0.f ? v[j] : 0.f;   // relu
            w = w * sc[j] + sh[j];               // BN (inference)
            best[j] = fmaxf(best[j], w);
        }
    }
#pragma unroll
    for (int j = 0; j < 4; ++j) atomicMax(&smax[h4 + j], f2k(best[j]));
    __syncthreads();
    if (threadIdx.x < H) atomicMax(&pooled_u[threadIdx.x], smax[threadIdx.x]);
}

// Kernel 4: out[j] = bd[j] + sum_h pooled[h] * Wd[h,j]
template <int H>
__global__ void final_matvec(const unsigned int* __restrict__ pooled_u,
                             const float* __restrict__ Wd,
                             const float* __restrict__ bd,
                             float* __restrict__ out,
                             int HOUT) {
    int j = threadIdx.x;
    if (j >= HOUT) return;
    float acc = bd[j];
#pragma unroll
    for (int hh = 0; hh < H; ++hh) acc += k2f(pooled_u[hh]) * Wd[hh * HOUT + j];
    out[j] = acc;
}

extern "C" void kernel_launch(void* const* d_in, const int* in_sizes, int n_in,
                              void* d_out, int out_size, void* d_ws, size_t ws_size,
                              hipStream_t stream) {
    const float* x     = (const float*)d_in[0];
    const float* e     = (const float*)d_in[1];
    const int*   src   = (const int*)d_in[2];
    const int*   dst   = (const int*)d_in[3];
    const float* Wk    = (const float*)d_in[4];
    const float* bk    = (const float*)d_in[5];
    const float* Wr    = (const float*)d_in[6];
    const float* br    = (const float*)d_in[7];
    const float* gamma = (const float*)d_in[8];
    const float* beta  = (const float*)d_in[9];
    const float* mmean = (const float*)d_in[10];
    const float* mvar  = (const float*)d_in[11];
    const float* Wd    = (const float*)d_in[12];
    const float* bd    = (const float*)d_in[13];

    constexpr int S = 8, F = 16, H = 16;
    const int E = in_sizes[2];
    const int N = in_sizes[0] / F;
    const int HOUT = in_sizes[13];  // 3

    // workspace layout
    _Float16* y2h = (_Float16*)d_ws;                       // N*(S+1)*H fp16
    float* agg = (float*)(y2h + (size_t)N * (S + 1) * H);  // N*H fp32
    unsigned int* pooled_u = (unsigned int*)(agg + (size_t)N * H);  // H

    const int T = 256;
    int nh = N * H;
    node_pre<S, F, H><<<(nh + T - 1) / T, T, 0, stream>>>(
        x, Wk, bk, Wr, br, y2h, agg, pooled_u, N);

    int eblocks = (E + 255) / 256;
    edge_scatter<S, H><<<eblocks, T, 0, stream>>>(
        e, src, dst, y2h, agg, E);

    bn_relu_max<H><<<1024, T, 0, stream>>>(agg, gamma, beta, mmean, mvar, pooled_u, N);

    final_matvec<H><<<1, 64, 0, stream>>>(pooled_u, Wd, bd, (float*)d_out, HOUT);
}